// Round 4
// 1445.106 us; speedup vs baseline: 1.0209x; 1.0209x over previous
//
// R7: R3 semantics (sc1/LIC comm, proven 1475us) + contiguous h-ring layout.
// R4-R6 (sc0/XCD fast path) produced zero counters across 3 rounds (likely
// hang -> wedged container) -> abandoned. R7 changes ONLY address math.
// Theory: R3's h stores are 32B partial-line chunks at 512B stride ->
// TCC write-allocate RMW: 4096 chunks/step/layer x 128B line fetch = 512KB
// fetch per step -> 524MB over the run == the unexplained FETCH (647MB vs
// 21MB real input). The RMW also sits on the pre-signal vmcnt(0) drain ->
// HBM-latency stall every step. Fix: h ring laid out [ring][gb][gg][b][ud]
// so each wg stores 256 consecutive dwords (base+tid, full lines, no RMW).
// Layout algebra: dword (gg,up) holds unit pair (gg*16+2up,+1) == dword
// (gg*8+up) of the unit vector, so scattering to LDS col k*8+(tid&7) keeps
// the IDENTITY unit order -> W tiles / biases / wlin / head unchanged.
#include <hip/hip_runtime.h>
#include <cstdint>

#define B_TOT 256
#define T_LEN 512
#define NX    40
#define NH    250
#define HP    256          // hidden padded (dummy units produce h=0, W cols 0)
#define XP    64           // x padded
#define K0    (XP + HP)    // 320  (layer0: [x | h1_prev])
#define K1    (HP + HP)    // 512  (layer1: [h1_t | h2_prev])
#define MB    32           // batches per wg
#define NU    16           // hidden units per wg
#define NR    64           // gate rows per wg (NU*4, r = lu*4 + gate; i,f,g,o)
#define RING  8            // broadcast ring depth
#define LDSK  520          // LDS K-stride in ushorts (16B aligned; 260 dwords)
#define SLOTS 16           // ints per slot (64B stride, own cache line)
#define NFLAG (2 * 8 * 16 * SLOTS)   // 4096 ints of flag slots (16KB)
#define RSTEP (B_TOT * HP / 2)       // 32768 dwords per ring slot
// h ring (dwords): slot*RSTEP + gb*4096 + gg*256 + eb*8 + up
//   where dword (gg,up) of batch eb = bf16 units (gg*16+2up, gg*16+2up+1)

typedef __attribute__((ext_vector_type(8))) short short8;
typedef __attribute__((ext_vector_type(4))) float float4v;

__device__ __forceinline__ unsigned short f2bf(float f) {
  unsigned u = __float_as_uint(f);
  u += 0x7FFFu + ((u >> 16) & 1u);          // RNE
  return (unsigned short)(u >> 16);
}
__device__ __forceinline__ float bf2f(unsigned short h) {
  return __uint_as_float(((unsigned)h) << 16);
}
__device__ __forceinline__ float sigm(float x) { return 1.0f / (1.0f + __expf(-x)); }
__device__ __forceinline__ float tanh_f(float x) {
  float e = __expf(-2.0f * fabsf(x));
  float t = (1.0f - e) / (1.0f + e);
  return copysignf(t, x);
}
__device__ __forceinline__ unsigned ld_lic(const unsigned* p) {   // sc1 dword load
  return __hip_atomic_load(p, __ATOMIC_RELAXED, __HIP_MEMORY_SCOPE_AGENT);
}

// ---------------------------------------------------------------------------
// Per-layer persistent loop. LAYER=0: x(40->64 pad)+h1_prev, K=320.
// LAYER=1: h1_t + h2_prev, K=512; gg==0 wgs also emit y[b, t-1] (after signal).
// Slot value = number of completed steps by that wg.
// ---------------------------------------------------------------------------
template <int KSTEPS, int LAYER>
__device__ __forceinline__ void run_layer(
    int tid, int gg, int b0, int u0,
    const float* __restrict__ x, float* __restrict__ out, float blinv,
    unsigned short* __restrict__ h1bc, unsigned short* __restrict__ h2bc,
    int* __restrict__ c0s, int* __restrict__ c1s, int* __restrict__ mys,
    unsigned short (*WL)[LDSK], unsigned short (*inA)[LDSK],
    float (*gbuf)[NR + 4], float* biasS, float* wlinS) {
  const int lane = tid & 63, wv = tid >> 6;
  const int quad = lane >> 4, l15 = lane & 15;
  const int Mt = wv & 1, Np = wv >> 1;   // wave -> (M-tile, N-tile-pair)
  const int gb = b0 >> 5;
  const int irow = tid >> 3, icol = tid & 7;   // gather->LDS scatter coords

  // Preload B fragments (constant across time): B[k][n]=WL[n-row][k];
  // lane layout n = lane&15, k = quad*8 + j.
  short8 bfrag[2][KSTEPS];
#pragma unroll
  for (int ks = 0; ks < KSTEPS; ++ks) {
#pragma unroll
    for (int i = 0; i < 2; ++i)
      bfrag[i][ks] = *(const short8*)&WL[Np * 32 + i * 16 + l15][ks * 32 + quad * 8];
  }

  // cell state for (batch b0+tid>>3, units u0+2*(tid&7), +1): fp32 registers
  float cA = 0.f, cB = 0.f;

#pragma unroll 1
  for (int t = 0; t < T_LEN; ++t) {
    // ---- wait for producers: wave0 lanes 0..31 poll one slot each (relaxed
    //      sc1 loads; NO fence — staging loads below read LIC themselves)
    if (wv == 0 && lane < 32) {
      const int* sl = ((lane < 16) ? c0s : c1s) + (lane & 15) * SLOTS;
      int thr;
      if (LAYER == 0) thr = (lane < 16) ? t : (t - RING + 1);
      else            thr = (lane < 16) ? (t + 1) : t;
      while (__hip_atomic_load(sl, __ATOMIC_RELAXED, __HIP_MEMORY_SCOPE_AGENT) < thr) {
        __builtin_amdgcn_s_sleep(1);
      }
    }
    __syncthreads();

    // ---- stage inputs into LDS (bf16). h via sc1 dword loads (LIC-fresh),
    //      coalesced: thread reads dwords tid + k*256 of the 16 KB block.
    if (LAYER == 0) {
      if (t > 0) {
        const unsigned* s1 = (const unsigned*)h1bc +
            ((size_t)((t - 1) & (RING - 1)) * RSTEP + (size_t)gb * 4096);
        unsigned v[16];
#pragma unroll
        for (int k = 0; k < 16; ++k) v[k] = ld_lic(s1 + tid + k * 256);
#pragma unroll
        for (int k = 0; k < 16; ++k)   // dword (gg=k, up=icol) of batch irow
          ((unsigned*)&inA[irow][0])[32 + k * 8 + icol] = v[k];   // +XP ushorts
      }
      if (tid < 128) {   // x[b, t, 0:40] -> inA[b][0:40] (40..63 stay zero)
        int b = tid >> 2, c = tid & 3;
        const float* xp = x + ((size_t)(b0 + b) * T_LEN + (size_t)t) * NX + c * 10;
#pragma unroll
        for (int j = 0; j < 10; ++j) inA[b][c * 10 + j] = f2bf(xp[j]);
      }
    } else {
      const unsigned* s1 = (const unsigned*)h1bc +
          ((size_t)(t & (RING - 1)) * RSTEP + (size_t)gb * 4096);
      unsigned va[16], vb[16];
#pragma unroll
      for (int k = 0; k < 16; ++k) va[k] = ld_lic(s1 + tid + k * 256);
      if (t > 0) {
        const unsigned* s2 = (const unsigned*)h2bc +
            ((size_t)((t - 1) & (RING - 1)) * RSTEP + (size_t)gb * 4096);
#pragma unroll
        for (int k = 0; k < 16; ++k) vb[k] = ld_lic(s2 + tid + k * 256);
      }
#pragma unroll
      for (int k = 0; k < 16; ++k) {
        unsigned* row = (unsigned*)&inA[irow][0];
        row[k * 8 + icol] = va[k];                    // h1 at ushort 0
        if (t > 0) row[128 + k * 8 + icol] = vb[k];   // h2 at ushort HP
      }
    }
    __syncthreads();

    // ---- gate GEMM: D[b][r] = sum_k inA[b][k] * WL[r][k] ----
    float4v acc0 = {0.f, 0.f, 0.f, 0.f};
    float4v acc1 = {0.f, 0.f, 0.f, 0.f};
#pragma unroll
    for (int ks = 0; ks < KSTEPS; ++ks) {
      short8 a = *(const short8*)&inA[Mt * 16 + l15][ks * 32 + quad * 8];
      acc0 = __builtin_amdgcn_mfma_f32_16x16x32_bf16(a, bfrag[0][ks], acc0, 0, 0, 0);
      acc1 = __builtin_amdgcn_mfma_f32_16x16x32_bf16(a, bfrag[1][ks], acc1, 0, 0, 0);
    }
    // dump C (row b = Mt*16+quad*4+reg, col r = Ntile*16 + l15)
#pragma unroll
    for (int reg = 0; reg < 4; ++reg) {
      gbuf[Mt * 16 + quad * 4 + reg][Np * 32 + l15] = acc0[reg];
      gbuf[Mt * 16 + quad * 4 + reg][Np * 32 + 16 + l15] = acc1[reg];
    }
    __syncthreads();

    // ---- gates + state update; write h (bf16, sc1 write-through to LIC).
    //      Store target = base + tid: 256 consecutive dwords per wg (full
    //      cache lines -> no TCC write-allocate RMW).
    {
      int eb = tid >> 3, up = tid & 7;
      float4v ga = *(const float4v*)&gbuf[eb][up * 8];
      float4v gv = *(const float4v*)&gbuf[eb][up * 8 + 4];
      float iA = sigm(ga[0] + biasS[up * 8 + 0]);
      float fA = sigm(ga[1] + biasS[up * 8 + 1]);
      float gA = tanh_f(ga[2] + biasS[up * 8 + 2]);
      float oA = sigm(ga[3] + biasS[up * 8 + 3]);
      cA = fA * cA + iA * gA;
      float hA = oA * tanh_f(cA);
      float iB = sigm(gv[0] + biasS[up * 8 + 4]);
      float fB = sigm(gv[1] + biasS[up * 8 + 5]);
      float gB = tanh_f(gv[2] + biasS[up * 8 + 6]);
      float oB = sigm(gv[3] + biasS[up * 8 + 7]);
      cB = fB * cB + iB * gB;
      float hB = oB * tanh_f(cB);
      unsigned hv = (unsigned)f2bf(hA) | ((unsigned)f2bf(hB) << 16);
      unsigned* dst = (unsigned*)(LAYER ? h2bc : h1bc);
      size_t di = (size_t)(t & (RING - 1)) * RSTEP + (size_t)gb * 4096 +
                  (size_t)gg * 256 + tid;
      __hip_atomic_store(dst + di, hv, __ATOMIC_RELAXED, __HIP_MEMORY_SCOPE_AGENT);
    }

    // barrier drains every wave's vmcnt(0) -> all sc1 h stores are LIC-visible;
    // then a RELAXED sc1 flag store suffices (no release/wbl2 needed: nothing
    // cross-wg-visible sits dirty in L2).
    __syncthreads();
    if (tid == 0)
      __hip_atomic_store(mys, t + 1, __ATOMIC_RELAXED, __HIP_MEMORY_SCOPE_AGENT);

    // ---- head: y[b, t-1] from staged h2[t-1] — AFTER signal (off crit path)
    if (LAYER == 1 && gg == 0 && t > 0) {
      int eb = tid >> 3, uc = tid & 7;
      float sum = 0.f;
#pragma unroll
      for (int j = 0; j < 4; ++j) {
        short8 hvv = *(const short8*)&inA[eb][HP + uc * 32 + j * 8];
#pragma unroll
        for (int e = 0; e < 8; ++e)
          sum += bf2f((unsigned short)hvv[e]) * wlinS[uc * 32 + j * 8 + e];
      }
      sum += __shfl_xor(sum, 1);
      sum += __shfl_xor(sum, 2);
      sum += __shfl_xor(sum, 4);
      if ((tid & 7) == 0)
        out[(size_t)(b0 + eb) * T_LEN + (t - 1)] = sigm(sum + blinv);
    }
  }

  // ---- epilogue: y[:, 511] after all layer1 wgs finished t=511 ----
  if (LAYER == 1 && gg == 0) {
    if (wv == 0 && lane < 16) {
      const int* sl = c1s + lane * SLOTS;
      while (__hip_atomic_load(sl, __ATOMIC_RELAXED, __HIP_MEMORY_SCOPE_AGENT) < T_LEN) {
        __builtin_amdgcn_s_sleep(1);
      }
    }
    __syncthreads();
    int eb = tid >> 3, uc = tid & 7;
    // units uc*32..uc*32+31 of batch b0+eb live in gg-blocks 2*uc and 2*uc+1:
    // dword = (2*uc+g)*256 + eb*8 + j  ->  units (2*uc+g)*16 + 2*j, +1
    const unsigned* base = (const unsigned*)h2bc +
        ((size_t)(511 & (RING - 1)) * RSTEP + (size_t)gb * 4096);
    float sum = 0.f;
#pragma unroll
    for (int g = 0; g < 2; ++g) {
      const unsigned* src = base + (size_t)(2 * uc + g) * 256 + eb * 8;
#pragma unroll
      for (int j = 0; j < 8; ++j) {
        unsigned dw = ld_lic(src + j);
        sum += bf2f((unsigned short)(dw & 0xFFFFu)) * wlinS[uc * 32 + g * 16 + 2 * j];
        sum += bf2f((unsigned short)(dw >> 16)) * wlinS[uc * 32 + g * 16 + 2 * j + 1];
      }
    }
    sum += __shfl_xor(sum, 1);
    sum += __shfl_xor(sum, 2);
    sum += __shfl_xor(sum, 4);
    if ((tid & 7) == 0)
      out[(size_t)(b0 + eb) * T_LEN + 511] = sigm(sum + blinv);
  }
}

// ---------------------------------------------------------------------------
extern "C" __global__ void __launch_bounds__(256, 1) lstm_persist(
    const float* __restrict__ x,
    const float* __restrict__ Wih0, const float* __restrict__ Whh0,
    const float* __restrict__ bih0, const float* __restrict__ bhh0,
    const float* __restrict__ Wih1, const float* __restrict__ Whh1,
    const float* __restrict__ bih1, const float* __restrict__ bhh1,
    const float* __restrict__ Wlin, const float* __restrict__ blin,
    float* __restrict__ out,
    unsigned short* __restrict__ h1bc, unsigned short* __restrict__ h2bc,
    int* __restrict__ cnt) {
  __shared__ unsigned short WL[NR][LDSK];    // 66560 B  bf16 [r][k], r = lu*4+gate
  __shared__ unsigned short inA[MB][LDSK];   // 33280 B  bf16 [b][k]
  __shared__ float gbuf[MB][NR + 4];         //  8704 B  fp32 gate preacts
  __shared__ float biasS[NR];
  __shared__ float wlinS[HP];

  const int tid = threadIdx.x;
  const int wg = blockIdx.x;
  const int layer = wg >> 7;
  const int gb = (wg >> 4) & 7;
  const int gg = wg & 15;
  const int b0 = gb * MB, u0 = gg * NU;

  // ---- one-time LDS fills ----
  {
    const float* Wih = layer ? Wih1 : Wih0;
    const float* Whh = layer ? Whh1 : Whh0;
    const float* bi = layer ? bih1 : bih0;
    const float* bh = layer ? bhh1 : bhh0;
    const int K = layer ? K1 : K0;
    const int xw = layer ? NH : NX;     // real width of input-part
    const int xofs = layer ? HP : XP;   // where h-part starts
    int r = tid >> 2, c = tid & 3;
    int lu = r >> 2, g = r & 3, ug = u0 + lu;
    int row = g * NH + ug;
    int kq = K >> 2;
    for (int k = c * kq; k < (c + 1) * kq; ++k) {
      float v = 0.f;
      if (ug < NH) {
        if (k < xw) v = Wih[(size_t)row * xw + k];
        else if (k >= xofs && k < xofs + NH) v = Whh[(size_t)row * NH + (k - xofs)];
      }
      WL[r][k] = f2bf(v);
    }
    if (tid < NR) {
      int lu2 = tid >> 2, g2 = tid & 3, ug2 = u0 + lu2;
      biasS[tid] = (ug2 < NH) ? (bi[g2 * NH + ug2] + bh[g2 * NH + ug2]) : 0.f;
    }
    if (tid < HP) wlinS[tid] = (tid < NH) ? Wlin[tid] : 0.f;
    for (int i = tid; i < MB * LDSK; i += 256) ((unsigned short*)inA)[i] = 0;
  }
  __syncthreads();

  float blinv = blin[0];
  int* c0s = cnt + gb * 16 * SLOTS;              // layer0 slots, batch-group gb
  int* c1s = cnt + (8 + gb) * 16 * SLOTS;        // layer1 slots
  int* mys = (layer ? c1s : c0s) + gg * SLOTS;   // own slot

  if (layer == 0)
    run_layer<K0 / 32, 0>(tid, gg, b0, u0, x, out, blinv, h1bc, h2bc,
                          c0s, c1s, mys, WL, inA, gbuf, biasS, wlinS);
  else
    run_layer<K1 / 32, 1>(tid, gg, b0, u0, x, out, blinv, h1bc, h2bc,
                          c0s, c1s, mys, WL, inA, gbuf, biasS, wlinS);
}

extern "C" __global__ void prep_zero(int* cnt) {
  int i = blockIdx.x * 256 + threadIdx.x;
  if (i < NFLAG)
    __hip_atomic_store(cnt + i, 0, __ATOMIC_RELAXED, __HIP_MEMORY_SCOPE_AGENT);
}

// ---------------------------------------------------------------------------
extern "C" void kernel_launch(void* const* d_in, const int* in_sizes, int n_in,
                              void* d_out, int out_size, void* d_ws, size_t ws_size,
                              hipStream_t stream) {
  const float* x    = (const float*)d_in[0];
  const float* Wih0 = (const float*)d_in[1];
  const float* Whh0 = (const float*)d_in[2];
  const float* bih0 = (const float*)d_in[3];
  const float* bhh0 = (const float*)d_in[4];
  const float* Wih1 = (const float*)d_in[5];
  const float* Whh1 = (const float*)d_in[6];
  const float* bih1 = (const float*)d_in[7];
  const float* bhh1 = (const float*)d_in[8];
  const float* Wlin = (const float*)d_in[9];
  const float* blin = (const float*)d_in[10];
  float* out = (float*)d_out;

  // workspace carve (same footprint as R3): h rings 2x2MB | slot counters 16KB
  unsigned short* h1bc = (unsigned short*)d_ws;
  unsigned short* h2bc = h1bc + (size_t)RING * B_TOT * HP;
  int* cnt = (int*)((char*)d_ws + 2u * (size_t)RING * B_TOT * HP * sizeof(unsigned short));

  hipLaunchKernelGGL(prep_zero, dim3(16), dim3(256), 0, stream, cnt);

  void* args[] = {&x, &Wih0, &Whh0, &bih0, &bhh0, &Wih1, &Whh1, &bih1, &bhh1,
                  &Wlin, &blin, &out, &h1bc, &h2bc, &cnt};
  hipLaunchCooperativeKernel((void*)lstm_persist, dim3(256), dim3(256), args, 0u, stream);
}

// Round 5
// 1250.954 us; speedup vs baseline: 1.1793x; 1.1552x over previous
//
// R8: XCD-clustered comm, compile-risk and hang-risk stripped.
// R4-R6 never produced counters; all three shared one unproven construct:
//   asm "s_getreg_b32 ..., hwreg(HW_REG_XCC_ID)" (symbolic name) -> likely
//   COMPILE failure, not a runtime hang. R8 uses the numeric builtin:
//   __builtin_amdgcn_s_getreg(63508)  // id=20(XCC_ID) | off=0<<6 | (32-1)<<11
// and the FAST path uses NO inline-asm memory ops:
//   - h stores: plain (write-through L1 -> local XCD L2; acked by the
//     compiler's vmcnt(0) drain at __syncthreads)
//   - h gather: ONE buffer_inv per step (L1 invalidate; R2 ran this per-step
//     on this harness) + plain loads (compiler-tracked waits, L2-served)
//   - flags: stores plain; polls stay R7's sc1 atomic loads (always fresh ->
//     hang impossible; a local sc1 load observes the locally-dirty L2 line)
// Role re-derivation (gb = own XCD) is runtime-verified (exactly 32 wgs per
// XCD, ids 0..7); any anomaly -> byte-identical R7 slow path (proven 1445us).
// R7 post-mortem: FETCH 648MB unchanged by contiguous stores -> RMW theory
// dead; FETCH is gather traffic, time is pure LIC latency chain (~6800cy/step:
// drain+flag+poll+gather+compute). Only lever = cut LIC RTs -> XCD-local L2.
#include <hip/hip_runtime.h>
#include <cstdint>

#define B_TOT 256
#define T_LEN 512
#define NX    40
#define NH    250
#define HP    256          // hidden padded (dummy units produce h=0, W cols 0)
#define XP    64           // x padded
#define K0    (XP + HP)    // 320  (layer0: [x | h1_prev])
#define K1    (HP + HP)    // 512  (layer1: [h1_t | h2_prev])
#define MB    32           // batches per wg
#define NU    16           // hidden units per wg
#define NR    64           // gate rows per wg (NU*4, r = lu*4 + gate; i,f,g,o)
#define RING  8            // broadcast ring depth
#define LDSK  520          // LDS K-stride in ushorts (16B aligned; 260 dwords)
#define SLOTS 16           // ints per slot (64B stride, own cache line)
#define NFLAG (2 * 8 * 16 * SLOTS)   // 4096 ints of flag slots (16KB)
#define RSTEP (B_TOT * HP / 2)       // 32768 dwords per ring slot
// h ring (dwords): slot*RSTEP + gb*4096 + gg*256 + eb*8 + up
//   where dword (gg,up) of batch eb = bf16 units (gg*16+2up, gg*16+2up+1)
// discovery state inside the flag region (padding ints; pollers only read
// int0 of each slot): xcd id of wg w at cnt[w*16+8], barrier at cnt[9].
#define XCD_AT(w) ((w) * SLOTS + 8)
#define BAR_IDX 9
// s_getreg imm: id | (offset<<6) | ((size-1)<<11); XCC_ID id=20, 32 bits.
#define GETREG_XCC 63508

typedef __attribute__((ext_vector_type(8))) short short8;
typedef __attribute__((ext_vector_type(4))) float float4v;

__device__ __forceinline__ unsigned short f2bf(float f) {
  unsigned u = __float_as_uint(f);
  u += 0x7FFFu + ((u >> 16) & 1u);          // RNE
  return (unsigned short)(u >> 16);
}
__device__ __forceinline__ float bf2f(unsigned short h) {
  return __uint_as_float(((unsigned)h) << 16);
}
__device__ __forceinline__ float sigm(float x) { return 1.0f / (1.0f + __expf(-x)); }
__device__ __forceinline__ float tanh_f(float x) {
  float e = __expf(-2.0f * fabsf(x));
  float t = (1.0f - e) / (1.0f + e);
  return copysignf(t, x);
}
__device__ __forceinline__ unsigned ld_lic(const unsigned* p) {   // sc1 dword load
  return __hip_atomic_load(p, __ATOMIC_RELAXED, __HIP_MEMORY_SCOPE_AGENT);
}
// CU-local L1 invalidate: subsequent plain loads are (at least) L2-fresh.
// buffer_inv proven to execute on this harness (R2 ran it per-step).
__device__ __forceinline__ void inv_l1() {
  asm volatile("buffer_inv\n\ts_waitcnt vmcnt(0)" ::: "memory");
  __builtin_amdgcn_sched_barrier(0);
}
template <bool FAST>
__device__ __forceinline__ unsigned ldh(const unsigned* p) {
  if (FAST) return *p;     // plain load, L2-served (post-inv)
  return ld_lic(p);
}
template <bool FAST>
__device__ __forceinline__ void sth(unsigned* p, unsigned v) {
  if (FAST) *p = v;        // plain store: write-through L1 -> local L2
  else __hip_atomic_store(p, v, __ATOMIC_RELAXED, __HIP_MEMORY_SCOPE_AGENT);
}

// ---------------------------------------------------------------------------
// Per-layer persistent loop. LAYER=0: x(40->64 pad)+h1_prev, K=320.
// LAYER=1: h1_t + h2_prev, K=512; gg==0 wgs also emit y[b, t-1] (after signal).
// Slot value = number of completed steps by that wg.
// ---------------------------------------------------------------------------
template <int KSTEPS, int LAYER, bool FAST>
__device__ __forceinline__ void run_layer(
    int tid, int gg, int b0, int u0,
    const float* __restrict__ x, float* __restrict__ out, float blinv,
    unsigned short* __restrict__ h1bc, unsigned short* __restrict__ h2bc,
    int* __restrict__ c0s, int* __restrict__ c1s, int* __restrict__ mys,
    unsigned short (*WL)[LDSK], unsigned short (*inA)[LDSK],
    float (*gbuf)[NR + 4], float* biasS, float* wlinS) {
  const int lane = tid & 63, wv = tid >> 6;
  const int quad = lane >> 4, l15 = lane & 15;
  const int Mt = wv & 1, Np = wv >> 1;   // wave -> (M-tile, N-tile-pair)
  const int gb = b0 >> 5;
  const int irow = tid >> 3, icol = tid & 7;   // gather->LDS scatter coords

  // Preload B fragments (constant across time): B[k][n]=WL[n-row][k];
  // lane layout n = lane&15, k = quad*8 + j.
  short8 bfrag[2][KSTEPS];
#pragma unroll
  for (int ks = 0; ks < KSTEPS; ++ks) {
#pragma unroll
    for (int i = 0; i < 2; ++i)
      bfrag[i][ks] = *(const short8*)&WL[Np * 32 + i * 16 + l15][ks * 32 + quad * 8];
  }

  // cell state for (batch b0+tid>>3, units u0+2*(tid&7), +1): fp32 registers
  float cA = 0.f, cB = 0.f;

#pragma unroll 1
  for (int t = 0; t < T_LEN; ++t) {
    // ---- wait for producers: wave0 lanes 0..31 poll one slot each (sc1
    //      relaxed loads in BOTH paths: always fresh -> no hang; in FAST the
    //      flag sits dirty in the local XCD L2, which an sc1 load observes).
    if (wv == 0 && lane < 32) {
      const int* sl = ((lane < 16) ? c0s : c1s) + (lane & 15) * SLOTS;
      int thr;
      if (LAYER == 0) thr = (lane < 16) ? t : (t - RING + 1);
      else            thr = (lane < 16) ? (t + 1) : t;
      while (__hip_atomic_load(sl, __ATOMIC_RELAXED, __HIP_MEMORY_SCOPE_AGENT) < thr) {
        __builtin_amdgcn_s_sleep(1);
      }
    }
    __syncthreads();
    // FAST data freshness: drop CU L1 so the plain gather loads read the XCD
    // L2 (where the producers' write-through stores live).
    if (FAST && (LAYER == 1 || t > 0)) inv_l1();

    // ---- stage inputs into LDS (bf16); coalesced dword gather ----
    if (LAYER == 0) {
      if (t > 0) {
        const unsigned* s1 = (const unsigned*)h1bc +
            ((size_t)((t - 1) & (RING - 1)) * RSTEP + (size_t)gb * 4096);
        unsigned v[16];
#pragma unroll
        for (int k = 0; k < 16; ++k) v[k] = ldh<FAST>(s1 + tid + k * 256);
#pragma unroll
        for (int k = 0; k < 16; ++k)   // dword (gg=k, up=icol) of batch irow
          ((unsigned*)&inA[irow][0])[32 + k * 8 + icol] = v[k];   // +XP ushorts
      }
      if (tid < 128) {   // x[b, t, 0:40] -> inA[b][0:40] (40..63 stay zero)
        int b = tid >> 2, c = tid & 3;
        const float* xp = x + ((size_t)(b0 + b) * T_LEN + (size_t)t) * NX + c * 10;
#pragma unroll
        for (int j = 0; j < 10; ++j) inA[b][c * 10 + j] = f2bf(xp[j]);
      }
    } else {
      const unsigned* s1 = (const unsigned*)h1bc +
          ((size_t)(t & (RING - 1)) * RSTEP + (size_t)gb * 4096);
      unsigned va[16], vb[16];
#pragma unroll
      for (int k = 0; k < 16; ++k) va[k] = ldh<FAST>(s1 + tid + k * 256);
      if (t > 0) {
        const unsigned* s2 = (const unsigned*)h2bc +
            ((size_t)((t - 1) & (RING - 1)) * RSTEP + (size_t)gb * 4096);
#pragma unroll
        for (int k = 0; k < 16; ++k) vb[k] = ldh<FAST>(s2 + tid + k * 256);
      }
#pragma unroll
      for (int k = 0; k < 16; ++k) {
        unsigned* row = (unsigned*)&inA[irow][0];
        row[k * 8 + icol] = va[k];                    // h1 at ushort 0
        if (t > 0) row[128 + k * 8 + icol] = vb[k];   // h2 at ushort HP
      }
    }
    __syncthreads();

    // ---- gate GEMM: D[b][r] = sum_k inA[b][k] * WL[r][k] ----
    float4v acc0 = {0.f, 0.f, 0.f, 0.f};
    float4v acc1 = {0.f, 0.f, 0.f, 0.f};
#pragma unroll
    for (int ks = 0; ks < KSTEPS; ++ks) {
      short8 a = *(const short8*)&inA[Mt * 16 + l15][ks * 32 + quad * 8];
      acc0 = __builtin_amdgcn_mfma_f32_16x16x32_bf16(a, bfrag[0][ks], acc0, 0, 0, 0);
      acc1 = __builtin_amdgcn_mfma_f32_16x16x32_bf16(a, bfrag[1][ks], acc1, 0, 0, 0);
    }
    // dump C (row b = Mt*16+quad*4+reg, col r = Ntile*16 + l15)
#pragma unroll
    for (int reg = 0; reg < 4; ++reg) {
      gbuf[Mt * 16 + quad * 4 + reg][Np * 32 + l15] = acc0[reg];
      gbuf[Mt * 16 + quad * 4 + reg][Np * 32 + 16 + l15] = acc1[reg];
    }
    __syncthreads();

    // ---- gates + state update; write h (bf16). Store = base+tid: 256
    //      consecutive dwords per wg (full lines). FAST: plain store ->
    //      local XCD L2; slow: sc1 write-through to LIC.
    {
      int eb = tid >> 3, up = tid & 7;
      float4v ga = *(const float4v*)&gbuf[eb][up * 8];
      float4v gv = *(const float4v*)&gbuf[eb][up * 8 + 4];
      float iA = sigm(ga[0] + biasS[up * 8 + 0]);
      float fA = sigm(ga[1] + biasS[up * 8 + 1]);
      float gA = tanh_f(ga[2] + biasS[up * 8 + 2]);
      float oA = sigm(ga[3] + biasS[up * 8 + 3]);
      cA = fA * cA + iA * gA;
      float hA = oA * tanh_f(cA);
      float iB = sigm(gv[0] + biasS[up * 8 + 4]);
      float fB = sigm(gv[1] + biasS[up * 8 + 5]);
      float gB = tanh_f(gv[2] + biasS[up * 8 + 6]);
      float oB = sigm(gv[3] + biasS[up * 8 + 7]);
      cB = fB * cB + iB * gB;
      float hB = oB * tanh_f(cB);
      unsigned hv = (unsigned)f2bf(hA) | ((unsigned)f2bf(hB) << 16);
      unsigned* dst = (unsigned*)(LAYER ? h2bc : h1bc);
      size_t di = (size_t)(t & (RING - 1)) * RSTEP + (size_t)gb * 4096 +
                  (size_t)gg * 256 + tid;
      sth<FAST>(dst + di, hv);
    }

    // barrier drains every wave's vmcnt(0) -> all h stores are at the
    // cluster's coherence point (FAST: local L2; slow: LIC); then a relaxed
    // flag store suffices.
    __syncthreads();
    if (tid == 0)
      sth<FAST>((unsigned*)mys, (unsigned)(t + 1));

    // ---- head: y[b, t-1] from staged h2[t-1] — AFTER signal (off crit path)
    if (LAYER == 1 && gg == 0 && t > 0) {
      int eb = tid >> 3, uc = tid & 7;
      float sum = 0.f;
#pragma unroll
      for (int j = 0; j < 4; ++j) {
        short8 hvv = *(const short8*)&inA[eb][HP + uc * 32 + j * 8];
#pragma unroll
        for (int e = 0; e < 8; ++e)
          sum += bf2f((unsigned short)hvv[e]) * wlinS[uc * 32 + j * 8 + e];
      }
      sum += __shfl_xor(sum, 1);
      sum += __shfl_xor(sum, 2);
      sum += __shfl_xor(sum, 4);
      if ((tid & 7) == 0)
        out[(size_t)(b0 + eb) * T_LEN + (t - 1)] = sigm(sum + blinv);
    }
  }

  // ---- epilogue: y[:, 511] after all layer1 wgs finished t=511 ----
  if (LAYER == 1 && gg == 0) {
    if (wv == 0 && lane < 16) {
      const int* sl = c1s + lane * SLOTS;
      while (__hip_atomic_load(sl, __ATOMIC_RELAXED, __HIP_MEMORY_SCOPE_AGENT) < T_LEN) {
        __builtin_amdgcn_s_sleep(1);
      }
    }
    __syncthreads();
    if (FAST) inv_l1();
    int eb = tid >> 3, uc = tid & 7;
    // units uc*32..uc*32+31 of batch b0+eb live in gg-blocks 2*uc and 2*uc+1:
    // dword = (2*uc+g)*256 + eb*8 + j  ->  units (2*uc+g)*16 + 2*j, +1
    const unsigned* base = (const unsigned*)h2bc +
        ((size_t)(511 & (RING - 1)) * RSTEP + (size_t)gb * 4096);
    float sum = 0.f;
#pragma unroll
    for (int g = 0; g < 2; ++g) {
      const unsigned* src = base + (size_t)(2 * uc + g) * 256 + eb * 8;
#pragma unroll
      for (int j = 0; j < 8; ++j) {
        unsigned dw = ldh<FAST>(src + j);
        sum += bf2f((unsigned short)(dw & 0xFFFFu)) * wlinS[uc * 32 + g * 16 + 2 * j];
        sum += bf2f((unsigned short)(dw >> 16)) * wlinS[uc * 32 + g * 16 + 2 * j + 1];
      }
    }
    sum += __shfl_xor(sum, 1);
    sum += __shfl_xor(sum, 2);
    sum += __shfl_xor(sum, 4);
    if ((tid & 7) == 0)
      out[(size_t)(b0 + eb) * T_LEN + 511] = sigm(sum + blinv);
  }
}

// ---------------------------------------------------------------------------
extern "C" __global__ void __launch_bounds__(256, 1) lstm_persist(
    const float* __restrict__ x,
    const float* __restrict__ Wih0, const float* __restrict__ Whh0,
    const float* __restrict__ bih0, const float* __restrict__ bhh0,
    const float* __restrict__ Wih1, const float* __restrict__ Whh1,
    const float* __restrict__ bih1, const float* __restrict__ bhh1,
    const float* __restrict__ Wlin, const float* __restrict__ blin,
    float* __restrict__ out,
    unsigned short* __restrict__ h1bc, unsigned short* __restrict__ h2bc,
    int* __restrict__ cnt) {
  __shared__ unsigned short WL[NR][LDSK];    // 66560 B  bf16 [r][k], r = lu*4+gate
  __shared__ unsigned short inA[MB][LDSK];   // 33280 B  bf16 [b][k]
  __shared__ float gbuf[MB][NR + 4];         //  8704 B  fp32 gate preacts
  __shared__ float biasS[NR];
  __shared__ float wlinS[HP];

  const int tid = threadIdx.x;
  const int wg = blockIdx.x;

  // ---- XCD discovery + dynamic clustering (one-time, off steady state) ----
  const unsigned xcc = ((unsigned)__builtin_amdgcn_s_getreg(GETREG_XCC)) & 15u;
  if (tid == 0) {
    __hip_atomic_store(cnt + XCD_AT(wg), (int)xcc, __ATOMIC_RELAXED,
                       __HIP_MEMORY_SCOPE_AGENT);
    __hip_atomic_fetch_add(cnt + BAR_IDX, 1, __ATOMIC_ACQ_REL,
                           __HIP_MEMORY_SCOPE_AGENT);
    while (__hip_atomic_load(cnt + BAR_IDX, __ATOMIC_ACQUIRE,
                             __HIP_MEMORY_SCOPE_AGENT) < 256)
      __builtin_amdgcn_s_sleep(8);
  }
  __syncthreads();
  int* sx = (int*)&gbuf[0][0];   // reuse gbuf as 256-int scratch
  sx[tid] = __hip_atomic_load(cnt + XCD_AT(tid), __ATOMIC_RELAXED,
                              __HIP_MEMORY_SCOPE_AGENT);
  __syncthreads();
  const int myv = sx[wg];
  int rank = 0;
  unsigned long long hist = 0;   // 8 byte-counters (no scratch array, rule #20)
  bool ok = true;
  for (int j = 0; j < 256; ++j) {
    int v = sx[j];
    if ((unsigned)v > 7u) { ok = false; v = 0; }
    hist += 1ull << (v * 8);
    if (v == myv && j < wg) rank++;
  }
  ok = ok && (hist == 0x2020202020202020ull);   // exactly 32 wgs per XCD
  __syncthreads();   // sx (gbuf) free for steady-state reuse

  // Roles: fast -> cluster = this XCD (gb = xcd id, rank -> layer/unit-group);
  //        slow -> R7's static mapping + sc1 comm ops (always correct).
  int layer, gb, gg;
  if (ok) { gb = myv;       layer = rank >> 4;    gg = rank & 15; }
  else    { layer = wg >> 7; gb = (wg >> 4) & 7;  gg = wg & 15;   }
  const int b0 = gb * MB, u0 = gg * NU;

  // ---- one-time LDS fills ----
  {
    const float* Wih = layer ? Wih1 : Wih0;
    const float* Whh = layer ? Whh1 : Whh0;
    const float* bi = layer ? bih1 : bih0;
    const float* bh = layer ? bhh1 : bhh0;
    const int K = layer ? K1 : K0;
    const int xw = layer ? NH : NX;     // real width of input-part
    const int xofs = layer ? HP : XP;   // where h-part starts
    int r = tid >> 2, c = tid & 3;
    int lu = r >> 2, g = r & 3, ug = u0 + lu;
    int row = g * NH + ug;
    int kq = K >> 2;
    for (int k = c * kq; k < (c + 1) * kq; ++k) {
      float v = 0.f;
      if (ug < NH) {
        if (k < xw) v = Wih[(size_t)row * xw + k];
        else if (k >= xofs && k < xofs + NH) v = Whh[(size_t)row * NH + (k - xofs)];
      }
      WL[r][k] = f2bf(v);
    }
    if (tid < NR) {
      int lu2 = tid >> 2, g2 = tid & 3, ug2 = u0 + lu2;
      biasS[tid] = (ug2 < NH) ? (bi[g2 * NH + ug2] + bh[g2 * NH + ug2]) : 0.f;
    }
    if (tid < HP) wlinS[tid] = (tid < NH) ? Wlin[tid] : 0.f;
    for (int i = tid; i < MB * LDSK; i += 256) ((unsigned short*)inA)[i] = 0;
  }
  __syncthreads();

  float blinv = blin[0];
  int* c0s = cnt + gb * 16 * SLOTS;              // layer0 slots, batch-group gb
  int* c1s = cnt + (8 + gb) * 16 * SLOTS;        // layer1 slots
  int* mys = (layer ? c1s : c0s) + gg * SLOTS;   // own slot

  if (ok) {
    if (layer == 0)
      run_layer<K0 / 32, 0, true>(tid, gg, b0, u0, x, out, blinv, h1bc, h2bc,
                                  c0s, c1s, mys, WL, inA, gbuf, biasS, wlinS);
    else
      run_layer<K1 / 32, 1, true>(tid, gg, b0, u0, x, out, blinv, h1bc, h2bc,
                                  c0s, c1s, mys, WL, inA, gbuf, biasS, wlinS);
  } else {
    if (layer == 0)
      run_layer<K0 / 32, 0, false>(tid, gg, b0, u0, x, out, blinv, h1bc, h2bc,
                                   c0s, c1s, mys, WL, inA, gbuf, biasS, wlinS);
    else
      run_layer<K1 / 32, 1, false>(tid, gg, b0, u0, x, out, blinv, h1bc, h2bc,
                                   c0s, c1s, mys, WL, inA, gbuf, biasS, wlinS);
  }
}

extern "C" __global__ void prep_zero(int* cnt) {
  int i = blockIdx.x * 256 + threadIdx.x;
  if (i < NFLAG)   // flag slots incl. embedded barrier/xcd-id padding ints
    __hip_atomic_store(cnt + i, 0, __ATOMIC_RELAXED, __HIP_MEMORY_SCOPE_AGENT);
}

// ---------------------------------------------------------------------------
extern "C" void kernel_launch(void* const* d_in, const int* in_sizes, int n_in,
                              void* d_out, int out_size, void* d_ws, size_t ws_size,
                              hipStream_t stream) {
  const float* x    = (const float*)d_in[0];
  const float* Wih0 = (const float*)d_in[1];
  const float* Whh0 = (const float*)d_in[2];
  const float* bih0 = (const float*)d_in[3];
  const float* bhh0 = (const float*)d_in[4];
  const float* Wih1 = (const float*)d_in[5];
  const float* Whh1 = (const float*)d_in[6];
  const float* bih1 = (const float*)d_in[7];
  const float* bhh1 = (const float*)d_in[8];
  const float* Wlin = (const float*)d_in[9];
  const float* blin = (const float*)d_in[10];
  float* out = (float*)d_out;

  // workspace carve (same footprint as R3/R7): h rings 2x2MB | counters 16KB
  unsigned short* h1bc = (unsigned short*)d_ws;
  unsigned short* h2bc = h1bc + (size_t)RING * B_TOT * HP;
  int* cnt = (int*)((char*)d_ws + 2u * (size_t)RING * B_TOT * HP * sizeof(unsigned short));

  hipLaunchKernelGGL(prep_zero, dim3(16), dim3(256), 0, stream, cnt);

  void* args[] = {&x, &Wih0, &Whh0, &bih0, &bhh0, &Wih1, &Whh1, &bih1, &bhh1,
                  &Wlin, &blin, &out, &h1bc, &h2bc, &cnt};
  hipLaunchCooperativeKernel((void*)lstm_persist, dim3(256), dim3(256), args, 0u, stream);
}